// Round 4
// baseline (731.056 us; speedup 1.0000x reference)
//
#include <hip/hip_runtime.h>
#include <stdint.h>

#define B_ 8
#define T_ 288
#define N_ 307
#define E_ 4912
#define D_ 64

// ================= one-workgroup GAT layer (device fn) =================
// p/ss/st/csr live in LDS; h buffers in global ws (L1/L2-resident, ~78 KB).
template <int H, int F, bool IDENT, bool LAST>
__device__ __forceinline__ void gat_layer(
    const float* __restrict__ hin, const float* __restrict__ W,
    const float* __restrict__ a_s, const float* __restrict__ a_t,
    const float* __restrict__ skipW, const float* __restrict__ b,
    float* __restrict__ hout,
    float* p_s, float* ss_s, float* st_s, const int* row_s, const int* csr_s) {
    const int tid = threadIdx.x;
    // ---- projection: p = hin @ W  (19648 outputs, 64-MAC each) ----
    for (int i = tid; i < N_ * 64; i += 1024) {
        int n = i >> 6, d = i & 63;
        const float* hr = hin + n * 64;
        const float* wc = W + d;
        float acc = 0.0f;
#pragma unroll 8
        for (int k = 0; k < 64; k++) acc += hr[k] * wc[k * 64];
        p_s[i] = acc;
    }
    __syncthreads();
    // ---- attention coefficients ss/st per (n,h) ----
    for (int i = tid; i < N_ * H; i += 1024) {
        int n = i / H, h = i % H;           // compile-time H
        float s0 = 0.0f, s1 = 0.0f;
#pragma unroll
        for (int f = 0; f < F; f++) {
            float pv = p_s[n * 64 + h * F + f];
            s0 += pv * a_s[h * F + f];
            s1 += pv * a_t[h * F + f];
        }
        ss_s[i] = s0;
        st_s[i] = s1;
    }
    __syncthreads();
    // ---- gather: softmax-weighted aggregate (no max-shift; scores O(1)) ----
    // wave-row mapping: i>>6 = n for a whole wave -> csr/ss reads broadcast,
    // p_s row read conflict-free.
    for (int i = tid; i < N_ * 64; i += 1024) {
        int n = i >> 6, d = i & 63;
        int h = d / F;                      // compile-time: F=8 -> d>>3 ; F=64 -> 0
        float stn = st_s[n * H + h];
        int rs = row_s[n], re = row_s[n + 1];
        float den = 0.0f, acc = 0.0f;
        for (int j = rs; j < re; j++) {
            int s = csr_s[j];
            float sc = ss_s[s * H + h] + stn;
            sc = sc > 0.0f ? sc : 0.2f * sc;     // leaky_relu(0.2)
            float ev = __expf(sc);
            den += ev;
            acc += p_s[s * 64 + d] * ev;
        }
        float val = acc / (den + 1e-16f);
        float sk;
        if (IDENT) {
            sk = hin[i];
        } else {
            const float* hr = hin + n * 64;
            const float* wc = skipW + d;
            sk = 0.0f;
#pragma unroll 8
            for (int k = 0; k < 64; k++) sk += hr[k] * wc[k * 64];
        }
        val += sk + b[d];
        if (!LAST) val = val > 0.0f ? val : expm1f(val);   // elu
        hout[i] = val;
    }
    __syncthreads();   // protect p_s/ss_s/st_s before next layer overwrites
}

// ================= everything-small kernel: 1 block x 1024 threads =================
__global__ __launch_bounds__(1024) void k_gat_all(
    const float* __restrict__ b_val, const float* __restrict__ nfeat,
    const float* __restrict__ W_sta, const float* __restrict__ b_sta,
    const float* __restrict__ ada, const int* __restrict__ src,
    const int* __restrict__ tgt,
    const float* __restrict__ g0W, const float* __restrict__ g0as,
    const float* __restrict__ g0at, const float* __restrict__ g0b,
    const float* __restrict__ g0skip,
    const float* __restrict__ g1W, const float* __restrict__ g1as,
    const float* __restrict__ g1at, const float* __restrict__ g1b,
    const float* __restrict__ g1skip,
    const float* __restrict__ g2W, const float* __restrict__ g2as,
    const float* __restrict__ g2at, const float* __restrict__ g2b,
    float* __restrict__ Qg, float* __restrict__ h0g, float* __restrict__ h1g,
    float* __restrict__ h2g, float* __restrict__ h3g) {
    __shared__ float p_s[N_ * 64];     // 78592 B
    __shared__ float ss_s[N_ * 8];     //  9824 B
    __shared__ float st_s[N_ * 8];     //  9824 B
    __shared__ int csr_s[E_];          // 19648 B
    __shared__ int row_s[N_ + 1];      //  1232 B
    __shared__ int cur_s[N_];          //  1228 B   (also the histogram)
    const int tid = threadIdx.x;

    // stage 0a: zero histogram
    for (int i = tid; i < N_; i += 1024) cur_s[i] = 0;
    __syncthreads();

    // stage 0b: Q table (global, only k_big reads it) + histogram + h0
    for (int i = tid; i < T_ * 64; i += 1024) {
        int t = i >> 6, d = i & 63;
        int k2 = d >> 1;
        float div = __expf(-(float)(2 * k2) * (9.210340371976184f / 64.0f) * 1.4426950408889634f);
        // note: __expf is 2^x on the VALU path via expf lowering; use precise form:
        div = expf(-(float)(2 * k2) * (9.210340371976184f / 64.0f));
        float ang = (float)t * div;
        float v = (d & 1) ? cosf(ang) : sinf(ang);
        Qg[i] = v + b_val[d];
    }
    for (int e = tid; e < E_; e += 1024) atomicAdd(&cur_s[tgt[e]], 1);
    for (int i = tid; i < N_ * 64; i += 1024) {
        int n = i >> 6, d = i & 63;
        const float* fr = nfeat + n * 32;
        const float* wc = W_sta + d;
        float a = b_sta[d] + ada[i];
#pragma unroll 8
        for (int k = 0; k < 32; k++) a += fr[k] * wc[k * 64];
        h0g[i] = a;
    }
    __syncthreads();

    // stage 0c: exclusive prefix scan of histogram (wave 0 only)
    if (tid < 64) {
        int run = 0;
#pragma unroll
        for (int c = 0; c < 5; c++) {
            int i = c * 64 + tid;
            int orig = (i < N_) ? cur_s[i] : 0;
            int v = orig;
#pragma unroll
            for (int off = 1; off < 64; off <<= 1) {
                int u = __shfl_up(v, off);
                if (tid >= off) v += u;
            }
            if (i < N_) row_s[i] = run + (v - orig);
            run += __shfl(v, 63);
        }
        if (tid == 0) row_s[N_] = run;   // == E_
    }
    __syncthreads();
    for (int i = tid; i < N_; i += 1024) cur_s[i] = row_s[i];
    __syncthreads();
    // stage 0d: scatter src ids into CSR order
    for (int e = tid; e < E_; e += 1024) {
        int t = tgt[e];
        int j = atomicAdd(&cur_s[t], 1);
        csr_s[j] = src[e];
    }
    __syncthreads();

    // 3 GAT layers
    gat_layer<8, 8, false, false>(h0g, g0W, g0as, g0at, g0skip, g0b, h1g,
                                  p_s, ss_s, st_s, row_s, csr_s);
    gat_layer<8, 8, false, false>(h1g, g1W, g1as, g1at, g1skip, g1b, h2g,
                                  p_s, ss_s, st_s, row_s, csr_s);
    gat_layer<1, 64, true, true>(h2g, g2W, g2as, g2at, nullptr, g2b, h3g,
                                 p_s, ss_s, st_s, row_s, csr_s);
}

// ================= broadcast: out[b,t,n,d] = x*Wv[d] + Q[t,d] + h3[n,d] =================
__global__ __launch_bounds__(256) void k_big(const float* __restrict__ x,
                                             const float* __restrict__ Q,
                                             const float* __restrict__ Wv,
                                             const float* __restrict__ h3,
                                             float* __restrict__ out) {
    int row = blockIdx.x * 32 + (threadIdx.x >> 3);   // (b,t,n) linear
    int l8 = threadIdx.x & 7;
    int d0 = l8 * 8;
    int n = row % N_;
    int bt = row / N_;
    int t = bt % T_;
    float xv = x[row];
    float4 q0 = *(const float4*)(Q + t * 64 + d0);
    float4 q1 = *(const float4*)(Q + t * 64 + d0 + 4);
    float4 g0 = *(const float4*)(h3 + n * 64 + d0);
    float4 g1 = *(const float4*)(h3 + n * 64 + d0 + 4);
    float4 w0 = *(const float4*)(Wv + d0);
    float4 w1 = *(const float4*)(Wv + d0 + 4);
    float4 o0, o1;
    o0.x = fmaf(xv, w0.x, q0.x + g0.x);
    o0.y = fmaf(xv, w0.y, q0.y + g0.y);
    o0.z = fmaf(xv, w0.z, q0.z + g0.z);
    o0.w = fmaf(xv, w0.w, q0.w + g0.w);
    o1.x = fmaf(xv, w1.x, q1.x + g1.x);
    o1.y = fmaf(xv, w1.y, q1.y + g1.y);
    o1.z = fmaf(xv, w1.z, q1.z + g1.z);
    o1.w = fmaf(xv, w1.w, q1.w + g1.w);
    float* op = out + row * 64 + d0;
    *(float4*)(op) = o0;
    *(float4*)(op + 4) = o1;
}

extern "C" void kernel_launch(void* const* d_in, const int* in_sizes, int n_in,
                              void* d_out, int out_size, void* d_ws, size_t ws_size,
                              hipStream_t stream) {
    const float* x      = (const float*)d_in[0];
    const float* nfeat  = (const float*)d_in[1];
    const int*   eidx   = (const int*)d_in[2];
    // d_in[3] edge_prob unused (load_trans_prob=False)
    const float* W_val  = (const float*)d_in[4];
    const float* b_val  = (const float*)d_in[5];
    const float* W_sta  = (const float*)d_in[6];
    const float* b_sta  = (const float*)d_in[7];
    const float* ada    = (const float*)d_in[8];
    const float* g0W    = (const float*)d_in[9];
    const float* g0as   = (const float*)d_in[10];
    const float* g0at   = (const float*)d_in[11];
    const float* g0b    = (const float*)d_in[12];
    const float* g1W    = (const float*)d_in[13];
    const float* g1as   = (const float*)d_in[14];
    const float* g1at   = (const float*)d_in[15];
    const float* g1b    = (const float*)d_in[16];
    const float* g2W    = (const float*)d_in[17];
    const float* g2as   = (const float*)d_in[18];
    const float* g2at   = (const float*)d_in[19];
    const float* g2b    = (const float*)d_in[20];
    const float* g0skip = (const float*)d_in[21];
    const float* g1skip = (const float*)d_in[22];
    (void)in_sizes; (void)n_in; (void)out_size; (void)ws_size;

    const int* src = eidx;
    const int* tgt = eidx + E_;

    // workspace (fp32)
    float* ws  = (float*)d_ws;
    float* Q   = ws;               // 288*64
    float* h0  = Q + T_ * 64;      // 307*64 each
    float* h1  = h0 + N_ * 64;
    float* h2  = h1 + N_ * 64;
    float* h3  = h2 + N_ * 64;

    // 1) all the small graph work in one workgroup
    k_gat_all<<<1, 1024, 0, stream>>>(b_val, nfeat, W_sta, b_sta, ada, src, tgt,
                                      g0W, g0as, g0at, g0b, g0skip,
                                      g1W, g1as, g1at, g1b, g1skip,
                                      g2W, g2as, g2at, g2b,
                                      Q, h0, h1, h2, h3);

    // 2) broadcast: 707328 rows, 32 rows/block
    const int ROWS = B_ * T_ * N_;                 // 707328
    k_big<<<ROWS / 32, 256, 0, stream>>>(x, Q, W_val, h3, (float*)d_out);
}